// Round 4
// baseline (1251.683 us; speedup 1.0000x reference)
//
#include <hip/hip_runtime.h>

#define N_USER 100000
#define N_ITEM 50000
#define NTOT   150000   // N_USER + N_ITEM
#define D      64
#define NE     2400000
#define LAYERS 3
#define BB     4096

#define SCAN_B 256
#define NBLK   ((NTOT + SCAN_B - 1) / SCAN_B)   // 586 blocks
static_assert(NBLK <= 1024, "scan2 single-block capacity");

// ---------------------------------------------------------------------------
// init: cur0 = concat(user_emb, item_emb)
// ---------------------------------------------------------------------------
__global__ __launch_bounds__(256) void init_emb(const float* __restrict__ ue,
                                                const float* __restrict__ ie,
                                                float* __restrict__ cur0) {
    int i = blockIdx.x * blockDim.x + threadIdx.x;
    const int total = NTOT * D / 4;
    if (i >= total) return;
    const int userElems = N_USER * D / 4;
    float4 v = (i < userElems) ? ((const float4*)ue)[i]
                               : ((const float4*)ie)[i - userElems];
    ((float4*)cur0)[i] = v;
}

// ---------------------------------------------------------------------------
// CSR build
// ---------------------------------------------------------------------------
__global__ __launch_bounds__(256) void hist_dst(const int* __restrict__ dst,
                                                int* __restrict__ counts) {
    int i = blockIdx.x * blockDim.x + threadIdx.x;
    int stride = gridDim.x * blockDim.x;
    for (; i < NE; i += stride) atomicAdd(&counts[dst[i]], 1);
}

__global__ __launch_bounds__(SCAN_B) void scan_block(const int* __restrict__ counts,
                                                     int* __restrict__ incl,
                                                     int* __restrict__ bsum) {
    __shared__ int s[SCAN_B];
    int tid = threadIdx.x;
    int i = blockIdx.x * SCAN_B + tid;
    s[tid] = (i < NTOT) ? counts[i] : 0;
    __syncthreads();
    #pragma unroll
    for (int off = 1; off < SCAN_B; off <<= 1) {
        int t = (tid >= off) ? s[tid - off] : 0;
        __syncthreads();
        s[tid] += t;
        __syncthreads();
    }
    if (i < NTOT) incl[i] = s[tid];
    if (tid == SCAN_B - 1) bsum[blockIdx.x] = s[tid];
}

__global__ __launch_bounds__(1024) void scan_bsum(int* __restrict__ bsum) {
    __shared__ int s[1024];
    int tid = threadIdx.x;
    s[tid] = (tid < NBLK) ? bsum[tid] : 0;
    __syncthreads();
    #pragma unroll
    for (int off = 1; off < 1024; off <<= 1) {
        int t = (tid >= off) ? s[tid - off] : 0;
        __syncthreads();
        s[tid] += t;
        __syncthreads();
    }
    if (tid < NBLK) bsum[tid] = s[tid];
}

__global__ __launch_bounds__(SCAN_B) void make_rowptr(const int* __restrict__ incl,
                                                      const int* __restrict__ counts,
                                                      const int* __restrict__ bsum,
                                                      int* __restrict__ rowptr) {
    int i = blockIdx.x * SCAN_B + threadIdx.x;
    if (i < NTOT) {
        int off = blockIdx.x ? bsum[blockIdx.x - 1] : 0;
        rowptr[i] = off + incl[i] - counts[i];
    }
    if (i == 0) rowptr[NTOT] = NE;
}

__global__ __launch_bounds__(256) void scatter_edges(const int*   __restrict__ src,
                                                     const int*   __restrict__ dst,
                                                     const float* __restrict__ val,
                                                     const int*   __restrict__ rowptr,
                                                     int*         __restrict__ fill,
                                                     int2*        __restrict__ srcval) {
    int i = blockIdx.x * blockDim.x + threadIdx.x;
    int stride = gridDim.x * blockDim.x;
    for (; i < NE; i += stride) {
        int d = dst[i];
        int pos = rowptr[d] + atomicAdd(&fill[d], 1);
        srcval[pos] = make_int2(src[i], __float_as_int(val[i]));
    }
}

// ---------------------------------------------------------------------------
// sort each row's edges by src (pure optimization: improves gather locality;
// any within-row permutation is numerically equivalent up to f32 reassoc).
// one THREAD per row, LDS staging, u64-packed (src<<32|valbits) insertion sort.
// ---------------------------------------------------------------------------
#define SORT_T   128
#define SORT_CAP 40
__global__ __launch_bounds__(SORT_T) void sort_rows(const int* __restrict__ rowptr,
                                                    int2* __restrict__ sv) {
    __shared__ long long buf[SORT_T * SORT_CAP];   // 40 KB
    long long* mine = &buf[(size_t)threadIdx.x * SORT_CAP];
    int row = blockIdx.x * SORT_T + threadIdx.x;
    if (row >= NTOT) return;
    int p = rowptr[row], e = rowptr[row + 1];
    int deg = e - p;
    if (deg <= 1) return;
    if (deg <= SORT_CAP) {
        for (int j = 0; j < deg; ++j) {
            int2 m = sv[p + j];
            mine[j] = ((long long)m.x << 32) | (unsigned int)m.y;
        }
        for (int j = 1; j < deg; ++j) {
            long long key = mine[j];
            int k = j - 1;
            while (k >= 0 && mine[k] > key) { mine[k + 1] = mine[k]; --k; }
            mine[k + 1] = key;
        }
        for (int j = 0; j < deg; ++j) {
            long long v = mine[j];
            sv[p + j] = make_int2((int)(v >> 32), (int)(unsigned int)(v & 0xffffffffll));
        }
    } else {
        // rare fallback (deg > 40 is ~6 sigma for Binomial(2.4M, 1/150K))
        for (int j = 1; j < deg; ++j) {
            int2 key = sv[p + j];
            int k = j - 1;
            while (k >= 0 && sv[p + k].x > key.x) { sv[p + k + 1] = sv[p + k]; --k; }
            sv[p + k + 1] = key;
        }
    }
}

// ---------------------------------------------------------------------------
// per-row CSR gather with 4-deep MLP unroll
// ---------------------------------------------------------------------------
__device__ __forceinline__ float rowGather(const int2* __restrict__ sv,
                                           int p, int e,
                                           const float* __restrict__ emb,
                                           int lane) {
    float acc = 0.0f;
    for (; p + 4 <= e; p += 4) {
        int2 m0 = sv[p + 0];
        int2 m1 = sv[p + 1];
        int2 m2 = sv[p + 2];
        int2 m3 = sv[p + 3];
        float x0 = emb[(size_t)m0.x * D + lane];
        float x1 = emb[(size_t)m1.x * D + lane];
        float x2 = emb[(size_t)m2.x * D + lane];
        float x3 = emb[(size_t)m3.x * D + lane];
        acc = fmaf(__int_as_float(m0.y), x0, acc);
        acc = fmaf(__int_as_float(m1.y), x1, acc);
        acc = fmaf(__int_as_float(m2.y), x2, acc);
        acc = fmaf(__int_as_float(m3.y), x3, acc);
    }
    for (; p < e; ++p) {
        int2 m = sv[p];
        acc = fmaf(__int_as_float(m.y), emb[(size_t)m.x * D + lane], acc);
    }
    return acc;
}

// ---------------------------------------------------------------------------
// fused layer: side = A_g @ cur ; sim = A_s @ cur ; attention mix -> nxt
// ---------------------------------------------------------------------------
__global__ __launch_bounds__(256) void layer_fused(const int2* __restrict__ svG,
                                                   const int*  __restrict__ rpG,
                                                   const int2* __restrict__ svS,
                                                   const int*  __restrict__ rpS,
                                                   const float* __restrict__ cur,
                                                   float*       __restrict__ nxt) {
    const int lane = threadIdx.x & 63;
    int row = blockIdx.x * (blockDim.x >> 6) + (threadIdx.x >> 6);
    if (row >= NTOT) return;
    size_t base = (size_t)row * D + lane;

    float c    = cur[base];
    float accG = rowGather(svG, rpG[row], rpG[row + 1], cur, lane);
    float accS = rowGather(svS, rpS[row], rpS[row + 1], cur, lane);

    float t1 = accG * c + accG;
    float t2 = accS * c + accS;
    #pragma unroll
    for (int off = 32; off; off >>= 1) {
        t1 += __shfl_xor(t1, off, 64);
        t2 += __shfl_xor(t2, off, 64);
    }
    float a1 = expf(t1 * (1.0f / 64.0f));
    float a2 = expf(t2 * (1.0f / 64.0f));
    float den = a1 + a2;
    float nv = (a1 / den) * accG + (a2 / den) * accS;
    nxt[base] = nv;
}

// ---------------------------------------------------------------------------
// final: mean of 4 layer embeddings at sampled rows, then dot
// ---------------------------------------------------------------------------
__global__ __launch_bounds__(256) void final_dot(const float* __restrict__ c0,
                                                 const float* __restrict__ c1,
                                                 const float* __restrict__ c2,
                                                 const float* __restrict__ c3,
                                                 const int* __restrict__ users,
                                                 const int* __restrict__ items,
                                                 float* __restrict__ out) {
    const int lane = threadIdx.x & 63;
    int b = blockIdx.x * (blockDim.x >> 6) + (threadIdx.x >> 6);
    if (b >= BB) return;
    size_t ub = (size_t)users[b] * D + lane;
    size_t vb = (size_t)(N_USER + items[b]) * D + lane;
    float x = (c0[ub] + c1[ub] + c2[ub] + c3[ub]) * 0.25f;
    float y = (c0[vb] + c1[vb] + c2[vb] + c3[vb]) * 0.25f;
    float p = x * y;
    #pragma unroll
    for (int off = 32; off; off >>= 1) p += __shfl_xor(p, off, 64);
    if (lane == 0) out[b] = p;
}

extern "C" void kernel_launch(void* const* d_in, const int* in_sizes, int n_in,
                              void* d_out, int out_size, void* d_ws, size_t ws_size,
                              hipStream_t stream) {
    const float* ue   = (const float*)d_in[0];
    const float* ie   = (const float*)d_in[1];
    const int*   gsrc = (const int*)d_in[2];
    const int*   gdst = (const int*)d_in[3];
    const float* gval = (const float*)d_in[4];
    const int*   ssrc = (const int*)d_in[5];
    const int*   sdst = (const int*)d_in[6];
    const float* sval = (const float*)d_in[7];
    const int*   users = (const int*)d_in[8];
    const int*   items = (const int*)d_in[9];
    float* out = (float*)d_out;

    // ---- workspace carve-up ----
    char* p = (char*)d_ws;
    auto carve = [&](size_t bytes) { char* r = p; p += (bytes + 255) & ~(size_t)255; return r; };
    const size_t rowElems = (size_t)NTOT * D;                    // 9.6M floats
    float* cur[LAYERS + 1];
    for (int l = 0; l <= LAYERS; ++l) cur[l] = (float*)carve(rowElems * 4);  // 153.6 MB
    int2*  svG   = (int2*)carve((size_t)NE * 8);                 // 19.2 MB
    int2*  svS   = (int2*)carve((size_t)NE * 8);                 // 19.2 MB
    int*   rpG   = (int*)carve((size_t)(NTOT + 1) * 4);
    int*   rpS   = (int*)carve((size_t)(NTOT + 1) * 4);
    int*   counts= (int*)carve((size_t)NTOT * 4);
    int*   incl  = (int*)carve((size_t)NTOT * 4);
    int*   fill  = (int*)carve((size_t)NTOT * 4);
    int*   bsum  = (int*)carve(4096);
    (void)ws_size;

    init_emb<<<(NTOT * D / 4 + 255) / 256, 256, 0, stream>>>(ue, ie, cur[0]);

    // ---- CSR build for both edge sets ----
    const int* esrc[2] = {gsrc, ssrc};
    const int* edst[2] = {gdst, sdst};
    const float* eval[2] = {gval, sval};
    int2* sv[2] = {svG, svS};
    int*  rp[2] = {rpG, rpS};
    for (int s = 0; s < 2; ++s) {
        hipMemsetAsync(counts, 0, (size_t)NTOT * 4, stream);
        hipMemsetAsync(fill,   0, (size_t)NTOT * 4, stream);
        hist_dst<<<2048, 256, 0, stream>>>(edst[s], counts);
        scan_block<<<NBLK, SCAN_B, 0, stream>>>(counts, incl, bsum);
        scan_bsum<<<1, 1024, 0, stream>>>(bsum);
        make_rowptr<<<NBLK, SCAN_B, 0, stream>>>(incl, counts, bsum, rp[s]);
        scatter_edges<<<2048, 256, 0, stream>>>(esrc[s], edst[s], eval[s], rp[s], fill, sv[s]);
        sort_rows<<<(NTOT + SORT_T - 1) / SORT_T, SORT_T, 0, stream>>>(rp[s], sv[s]);
    }

    // ---- 3 fused propagation layers (double-buffered) ----
    for (int l = 0; l < LAYERS; ++l) {
        layer_fused<<<(NTOT + 3) / 4, 256, 0, stream>>>(svG, rpG, svS, rpS,
                                                        cur[l], cur[l + 1]);
    }

    final_dot<<<BB / 4, 256, 0, stream>>>(cur[0], cur[1], cur[2], cur[3],
                                          users, items, out);
}

// Round 6
// 1018.743 us; speedup vs baseline: 1.2287x; 1.2287x over previous
//
#include <hip/hip_runtime.h>

#define N_USER 100000
#define N_ITEM 50000
#define NTOT   150000   // N_USER + N_ITEM
#define D      64
#define NE     2400000
#define LAYERS 3
#define BB     4096

#define SCAN_B 256
#define NBLK   ((NTOT + SCAN_B - 1) / SCAN_B)   // 586 blocks
static_assert(NBLK <= 1024, "scan2 single-block capacity");

// ---------------------------------------------------------------------------
// init: cur0 = concat(user_emb, item_emb)
// ---------------------------------------------------------------------------
__global__ __launch_bounds__(256) void init_emb(const float* __restrict__ ue,
                                                const float* __restrict__ ie,
                                                float* __restrict__ cur0) {
    int i = blockIdx.x * blockDim.x + threadIdx.x;
    const int total = NTOT * D / 4;
    if (i >= total) return;
    const int userElems = N_USER * D / 4;
    float4 v = (i < userElems) ? ((const float4*)ue)[i]
                               : ((const float4*)ie)[i - userElems];
    ((float4*)cur0)[i] = v;
}

// ---------------------------------------------------------------------------
// CSR build
// ---------------------------------------------------------------------------
__global__ __launch_bounds__(256) void hist_dst(const int* __restrict__ dst,
                                                int* __restrict__ counts) {
    int i = blockIdx.x * blockDim.x + threadIdx.x;
    int stride = gridDim.x * blockDim.x;
    for (; i < NE; i += stride) atomicAdd(&counts[dst[i]], 1);
}

__global__ __launch_bounds__(SCAN_B) void scan_block(const int* __restrict__ counts,
                                                     int* __restrict__ incl,
                                                     int* __restrict__ bsum) {
    __shared__ int s[SCAN_B];
    int tid = threadIdx.x;
    int i = blockIdx.x * SCAN_B + tid;
    s[tid] = (i < NTOT) ? counts[i] : 0;
    __syncthreads();
    #pragma unroll
    for (int off = 1; off < SCAN_B; off <<= 1) {
        int t = (tid >= off) ? s[tid - off] : 0;
        __syncthreads();
        s[tid] += t;
        __syncthreads();
    }
    if (i < NTOT) incl[i] = s[tid];
    if (tid == SCAN_B - 1) bsum[blockIdx.x] = s[tid];
}

__global__ __launch_bounds__(1024) void scan_bsum(int* __restrict__ bsum) {
    __shared__ int s[1024];
    int tid = threadIdx.x;
    s[tid] = (tid < NBLK) ? bsum[tid] : 0;
    __syncthreads();
    #pragma unroll
    for (int off = 1; off < 1024; off <<= 1) {
        int t = (tid >= off) ? s[tid - off] : 0;
        __syncthreads();
        s[tid] += t;
        __syncthreads();
    }
    if (tid < NBLK) bsum[tid] = s[tid];
}

__global__ __launch_bounds__(SCAN_B) void make_rowptr(const int* __restrict__ incl,
                                                      const int* __restrict__ counts,
                                                      const int* __restrict__ bsum,
                                                      int* __restrict__ rowptr) {
    int i = blockIdx.x * SCAN_B + threadIdx.x;
    if (i < NTOT) {
        int off = blockIdx.x ? bsum[blockIdx.x - 1] : 0;
        rowptr[i] = off + incl[i] - counts[i];
    }
    if (i == 0) rowptr[NTOT] = NE;
}

__global__ __launch_bounds__(256) void scatter_edges(const int*   __restrict__ src,
                                                     const int*   __restrict__ dst,
                                                     const float* __restrict__ val,
                                                     const int*   __restrict__ rowptr,
                                                     int*         __restrict__ fill,
                                                     int2*        __restrict__ srcval) {
    int i = blockIdx.x * blockDim.x + threadIdx.x;
    int stride = gridDim.x * blockDim.x;
    for (; i < NE; i += stride) {
        int d = dst[i];
        int pos = rowptr[d] + atomicAdd(&fill[d], 1);
        srcval[pos] = make_int2(src[i], __float_as_int(val[i]));
    }
}

// ---------------------------------------------------------------------------
// tail gather (4-deep), takes initial accumulator
// ---------------------------------------------------------------------------
__device__ __forceinline__ float rowGather(const int2* __restrict__ sv,
                                           int p, int e,
                                           const float* __restrict__ emb,
                                           int lane, float acc) {
    for (; p + 4 <= e; p += 4) {
        int2 m0 = sv[p + 0];
        int2 m1 = sv[p + 1];
        int2 m2 = sv[p + 2];
        int2 m3 = sv[p + 3];
        float x0 = emb[(size_t)m0.x * D + lane];
        float x1 = emb[(size_t)m1.x * D + lane];
        float x2 = emb[(size_t)m2.x * D + lane];
        float x3 = emb[(size_t)m3.x * D + lane];
        acc = fmaf(__int_as_float(m0.y), x0, acc);
        acc = fmaf(__int_as_float(m1.y), x1, acc);
        acc = fmaf(__int_as_float(m2.y), x2, acc);
        acc = fmaf(__int_as_float(m3.y), x3, acc);
    }
    for (; p < e; ++p) {
        int2 m = sv[p];
        acc = fmaf(__int_as_float(m.y), emb[(size_t)m.x * D + lane], acc);
    }
    return acc;
}

// ---------------------------------------------------------------------------
// fused layer with dual-stream gather: 4 graph + 4 sim gathers in flight
// one wave per row, lane = d
// ---------------------------------------------------------------------------
__global__ __launch_bounds__(256) void layer_fused(const int2* __restrict__ svG,
                                                   const int*  __restrict__ rpG,
                                                   const int2* __restrict__ svS,
                                                   const int*  __restrict__ rpS,
                                                   const float* __restrict__ cur,
                                                   float*       __restrict__ nxt) {
    const int lane = threadIdx.x & 63;
    int row = blockIdx.x * (blockDim.x >> 6) + (threadIdx.x >> 6);
    if (row >= NTOT) return;
    size_t base = (size_t)row * D + lane;

    int pG = rpG[row], eG = rpG[row + 1];
    int pS = rpS[row], eS = rpS[row + 1];
    float c = cur[base];
    float accG = 0.0f, accS = 0.0f;

    // dual-stream main loop: 8 independent gathers in flight
    while (pG + 4 <= eG && pS + 4 <= eS) {
        int2 g0 = svG[pG + 0];
        int2 g1 = svG[pG + 1];
        int2 g2 = svG[pG + 2];
        int2 g3 = svG[pG + 3];
        int2 s0 = svS[pS + 0];
        int2 s1 = svS[pS + 1];
        int2 s2 = svS[pS + 2];
        int2 s3 = svS[pS + 3];
        float xg0 = cur[(size_t)g0.x * D + lane];
        float xg1 = cur[(size_t)g1.x * D + lane];
        float xg2 = cur[(size_t)g2.x * D + lane];
        float xg3 = cur[(size_t)g3.x * D + lane];
        float xs0 = cur[(size_t)s0.x * D + lane];
        float xs1 = cur[(size_t)s1.x * D + lane];
        float xs2 = cur[(size_t)s2.x * D + lane];
        float xs3 = cur[(size_t)s3.x * D + lane];
        accG = fmaf(__int_as_float(g0.y), xg0, accG);
        accG = fmaf(__int_as_float(g1.y), xg1, accG);
        accG = fmaf(__int_as_float(g2.y), xg2, accG);
        accG = fmaf(__int_as_float(g3.y), xg3, accG);
        accS = fmaf(__int_as_float(s0.y), xs0, accS);
        accS = fmaf(__int_as_float(s1.y), xs1, accS);
        accS = fmaf(__int_as_float(s2.y), xs2, accS);
        accS = fmaf(__int_as_float(s3.y), xs3, accS);
        pG += 4; pS += 4;
    }
    accG = rowGather(svG, pG, eG, cur, lane, accG);
    accS = rowGather(svS, pS, eS, cur, lane, accS);

    float t1 = accG * c + accG;
    float t2 = accS * c + accS;
    #pragma unroll
    for (int off = 32; off; off >>= 1) {
        t1 += __shfl_xor(t1, off, 64);
        t2 += __shfl_xor(t2, off, 64);
    }
    float a1 = expf(t1 * (1.0f / 64.0f));
    float a2 = expf(t2 * (1.0f / 64.0f));
    float den = a1 + a2;
    float nv = (a1 / den) * accG + (a2 / den) * accS;
    nxt[base] = nv;
}

// ---------------------------------------------------------------------------
// final: mean of 4 layer embeddings at sampled rows, then dot
// ---------------------------------------------------------------------------
__global__ __launch_bounds__(256) void final_dot(const float* __restrict__ c0,
                                                 const float* __restrict__ c1,
                                                 const float* __restrict__ c2,
                                                 const float* __restrict__ c3,
                                                 const int* __restrict__ users,
                                                 const int* __restrict__ items,
                                                 float* __restrict__ out) {
    const int lane = threadIdx.x & 63;
    int b = blockIdx.x * (blockDim.x >> 6) + (threadIdx.x >> 6);
    if (b >= BB) return;
    size_t ub = (size_t)users[b] * D + lane;
    size_t vb = (size_t)(N_USER + items[b]) * D + lane;
    float x = (c0[ub] + c1[ub] + c2[ub] + c3[ub]) * 0.25f;
    float y = (c0[vb] + c1[vb] + c2[vb] + c3[vb]) * 0.25f;
    float p = x * y;
    #pragma unroll
    for (int off = 32; off; off >>= 1) p += __shfl_xor(p, off, 64);
    if (lane == 0) out[b] = p;
}

extern "C" void kernel_launch(void* const* d_in, const int* in_sizes, int n_in,
                              void* d_out, int out_size, void* d_ws, size_t ws_size,
                              hipStream_t stream) {
    const float* ue   = (const float*)d_in[0];
    const float* ie   = (const float*)d_in[1];
    const int*   gsrc = (const int*)d_in[2];
    const int*   gdst = (const int*)d_in[3];
    const float* gval = (const float*)d_in[4];
    const int*   ssrc = (const int*)d_in[5];
    const int*   sdst = (const int*)d_in[6];
    const float* sval = (const float*)d_in[7];
    const int*   users = (const int*)d_in[8];
    const int*   items = (const int*)d_in[9];
    float* out = (float*)d_out;

    // ---- workspace carve-up ----
    char* p = (char*)d_ws;
    auto carve = [&](size_t bytes) { char* r = p; p += (bytes + 255) & ~(size_t)255; return r; };
    const size_t rowElems = (size_t)NTOT * D;                    // 9.6M floats
    float* cur[LAYERS + 1];
    for (int l = 0; l <= LAYERS; ++l) cur[l] = (float*)carve(rowElems * 4);  // 153.6 MB
    int2*  svG   = (int2*)carve((size_t)NE * 8);                 // 19.2 MB
    int2*  svS   = (int2*)carve((size_t)NE * 8);                 // 19.2 MB
    int*   rpG   = (int*)carve((size_t)(NTOT + 1) * 4);
    int*   rpS   = (int*)carve((size_t)(NTOT + 1) * 4);
    // counts+fill carved as ONE block so a single memset covers both exactly
    // (round-5 bug: separate carves leave a 64B alignment gap; the tail of
    //  fill stayed poisoned -> wild scatter -> device abort)
    int*   counts= (int*)carve((size_t)NTOT * 2 * 4);
    int*   fill  = counts + NTOT;
    int*   incl  = (int*)carve((size_t)NTOT * 4);
    int*   bsum  = (int*)carve(4096);
    (void)ws_size;

    init_emb<<<(NTOT * D / 4 + 255) / 256, 256, 0, stream>>>(ue, ie, cur[0]);

    // ---- CSR build for both edge sets ----
    const int* esrc[2] = {gsrc, ssrc};
    const int* edst[2] = {gdst, sdst};
    const float* eval[2] = {gval, sval};
    int2* sv[2] = {svG, svS};
    int*  rp[2] = {rpG, rpS};
    for (int s = 0; s < 2; ++s) {
        hipMemsetAsync(counts, 0, (size_t)NTOT * 2 * 4, stream);  // counts + fill
        hist_dst<<<2048, 256, 0, stream>>>(edst[s], counts);
        scan_block<<<NBLK, SCAN_B, 0, stream>>>(counts, incl, bsum);
        scan_bsum<<<1, 1024, 0, stream>>>(bsum);
        make_rowptr<<<NBLK, SCAN_B, 0, stream>>>(incl, counts, bsum, rp[s]);
        scatter_edges<<<2048, 256, 0, stream>>>(esrc[s], edst[s], eval[s], rp[s], fill, sv[s]);
    }

    // ---- 3 fused propagation layers (double-buffered) ----
    for (int l = 0; l < LAYERS; ++l) {
        layer_fused<<<(NTOT + 3) / 4, 256, 0, stream>>>(svG, rpG, svS, rpS,
                                                        cur[l], cur[l + 1]);
    }

    final_dot<<<BB / 4, 256, 0, stream>>>(cur[0], cur[1], cur[2], cur[3],
                                          users, items, out);
}

// Round 7
// 734.675 us; speedup vs baseline: 1.7037x; 1.3867x over previous
//
#include <hip/hip_runtime.h>

#define N_USER 100000
#define N_ITEM 50000
#define NTOT   150000   // N_USER + N_ITEM
#define D      64
#define NE     2400000
#define LAYERS 3
#define BB     4096

#define NBUCK  586      // ceil(NTOT/256) buckets of 256 rows
#define BCAP   6144     // bucket capacity (mean 4096, sigma 64 -> +32 sigma)
#define PART_EDGES 8192
#define PART_GRID  ((NE + PART_EDGES - 1) / PART_EDGES)   // 293

// ---------------------------------------------------------------------------
// init: cur0 = concat(user_emb, item_emb)
// ---------------------------------------------------------------------------
__global__ __launch_bounds__(256) void init_emb(const float* __restrict__ ue,
                                                const float* __restrict__ ie,
                                                float* __restrict__ cur0) {
    int i = blockIdx.x * blockDim.x + threadIdx.x;
    const int total = NTOT * D / 4;
    if (i >= total) return;
    const int userElems = N_USER * D / 4;
    float4 v = (i < userElems) ? ((const float4*)ue)[i]
                               : ((const float4*)ie)[i - userElems];
    ((float4*)cur0)[i] = v;
}

// ---------------------------------------------------------------------------
// Radix CSR build, level 1: partition edges into 586 dst-buckets.
// Packed payload: x = src | (dst&255)<<18  (src<2^18), y = val bits.
// Per-block LDS histogram -> one global atomic per (block,bucket) -> append.
// Only 586 open write regions: tail lines stay L2-resident.
// ---------------------------------------------------------------------------
__global__ __launch_bounds__(256) void partition_edges(const int*   __restrict__ src,
                                                       const int*   __restrict__ dst,
                                                       const float* __restrict__ val,
                                                       int*  __restrict__ bucketCount,
                                                       int2* __restrict__ bucketBuf) {
    __shared__ int hist[NBUCK];
    __shared__ int base[NBUCK];
    int lo = blockIdx.x * PART_EDGES;
    int hi = min(NE, lo + PART_EDGES);
    for (int i = threadIdx.x; i < NBUCK; i += 256) hist[i] = 0;
    __syncthreads();
    for (int i = lo + threadIdx.x; i < hi; i += 256)
        atomicAdd(&hist[dst[i] >> 8], 1);
    __syncthreads();
    for (int i = threadIdx.x; i < NBUCK; i += 256) {
        int c = hist[i];
        base[i] = c ? atomicAdd(&bucketCount[i], c) : 0;
        hist[i] = 0;
    }
    __syncthreads();
    for (int i = lo + threadIdx.x; i < hi; i += 256) {
        int d = dst[i];
        int b = d >> 8;
        int r = atomicAdd(&hist[b], 1);
        int slot = base[b] + r;
        if (slot < BCAP)
            bucketBuf[(size_t)b * BCAP + slot] =
                make_int2(src[i] | ((d & 255) << 18), __float_as_int(val[i]));
    }
}

// ---------------------------------------------------------------------------
// level 2a: exclusive scan of 586 bucket counts -> bucketBase; rowptr[NTOT]=NE
// ---------------------------------------------------------------------------
__global__ __launch_bounds__(1024) void bucket_scan(const int* __restrict__ bucketCount,
                                                    int* __restrict__ bucketBase,
                                                    int* __restrict__ rowptr) {
    __shared__ int s[1024];
    int tid = threadIdx.x;
    int c = (tid < NBUCK) ? bucketCount[tid] : 0;
    s[tid] = c;
    __syncthreads();
    #pragma unroll
    for (int off = 1; off < 1024; off <<= 1) {
        int t = (tid >= off) ? s[tid - off] : 0;
        __syncthreads();
        s[tid] += t;
        __syncthreads();
    }
    if (tid < NBUCK) bucketBase[tid] = s[tid] - c;   // exclusive
    if (tid == 0) rowptr[NTOT] = NE;
}

// ---------------------------------------------------------------------------
// level 2b: one block per bucket. LDS-stage the bucket's edges, build the
// 256-row sub-CSR in LDS, emit rowptr + row-grouped edges (contiguous 32KB
// region per bucket -> all scatter randomness confined to LDS/L2).
// ---------------------------------------------------------------------------
__global__ __launch_bounds__(256) void bucket_build(const int2* __restrict__ bucketBuf,
                                                    const int*  __restrict__ bucketCount,
                                                    const int*  __restrict__ bucketBase,
                                                    int*  __restrict__ rowptr,
                                                    int2* __restrict__ sv) {
    __shared__ int2 e[BCAP];        // 48 KB
    __shared__ int rhist[256];
    __shared__ int rscan[256];
    int b   = blockIdx.x;
    int cnt = min(bucketCount[b], BCAP);
    int obase = bucketBase[b];
    const int2* in = &bucketBuf[(size_t)b * BCAP];
    int tid = threadIdx.x;

    for (int i = tid; i < cnt; i += 256) e[i] = in[i];
    rhist[tid] = 0;
    __syncthreads();
    for (int i = tid; i < cnt; i += 256)
        atomicAdd(&rhist[(e[i].x >> 18) & 255], 1);
    __syncthreads();
    int myc = rhist[tid];
    rscan[tid] = myc;
    __syncthreads();
    #pragma unroll
    for (int off = 1; off < 256; off <<= 1) {
        int t = (tid >= off) ? rscan[tid - off] : 0;
        __syncthreads();
        rscan[tid] += t;
        __syncthreads();
    }
    int excl = rscan[tid] - myc;
    int grow = b * 256 + tid;
    if (grow < NTOT) rowptr[grow] = obase + excl;
    rhist[tid] = excl;              // running fill cursor per row
    __syncthreads();
    for (int i = tid; i < cnt; i += 256) {
        int row = (e[i].x >> 18) & 255;
        int pos = obase + atomicAdd(&rhist[row], 1);
        sv[pos] = make_int2(e[i].x & 0x3ffff, e[i].y);
    }
}

// ---------------------------------------------------------------------------
// tail gather (4-deep), takes initial accumulator
// ---------------------------------------------------------------------------
__device__ __forceinline__ float rowGather(const int2* __restrict__ sv,
                                           int p, int e,
                                           const float* __restrict__ emb,
                                           int lane, float acc) {
    for (; p + 4 <= e; p += 4) {
        int2 m0 = sv[p + 0];
        int2 m1 = sv[p + 1];
        int2 m2 = sv[p + 2];
        int2 m3 = sv[p + 3];
        float x0 = emb[(size_t)m0.x * D + lane];
        float x1 = emb[(size_t)m1.x * D + lane];
        float x2 = emb[(size_t)m2.x * D + lane];
        float x3 = emb[(size_t)m3.x * D + lane];
        acc = fmaf(__int_as_float(m0.y), x0, acc);
        acc = fmaf(__int_as_float(m1.y), x1, acc);
        acc = fmaf(__int_as_float(m2.y), x2, acc);
        acc = fmaf(__int_as_float(m3.y), x3, acc);
    }
    for (; p < e; ++p) {
        int2 m = sv[p];
        acc = fmaf(__int_as_float(m.y), emb[(size_t)m.x * D + lane], acc);
    }
    return acc;
}

// ---------------------------------------------------------------------------
// fused layer with dual-stream gather: 4 graph + 4 sim gathers in flight
// ---------------------------------------------------------------------------
__global__ __launch_bounds__(256) void layer_fused(const int2* __restrict__ svG,
                                                   const int*  __restrict__ rpG,
                                                   const int2* __restrict__ svS,
                                                   const int*  __restrict__ rpS,
                                                   const float* __restrict__ cur,
                                                   float*       __restrict__ nxt) {
    const int lane = threadIdx.x & 63;
    int row = blockIdx.x * (blockDim.x >> 6) + (threadIdx.x >> 6);
    if (row >= NTOT) return;
    size_t base = (size_t)row * D + lane;

    int pG = rpG[row], eG = rpG[row + 1];
    int pS = rpS[row], eS = rpS[row + 1];
    float c = cur[base];
    float accG = 0.0f, accS = 0.0f;

    while (pG + 4 <= eG && pS + 4 <= eS) {
        int2 g0 = svG[pG + 0];
        int2 g1 = svG[pG + 1];
        int2 g2 = svG[pG + 2];
        int2 g3 = svG[pG + 3];
        int2 s0 = svS[pS + 0];
        int2 s1 = svS[pS + 1];
        int2 s2 = svS[pS + 2];
        int2 s3 = svS[pS + 3];
        float xg0 = cur[(size_t)g0.x * D + lane];
        float xg1 = cur[(size_t)g1.x * D + lane];
        float xg2 = cur[(size_t)g2.x * D + lane];
        float xg3 = cur[(size_t)g3.x * D + lane];
        float xs0 = cur[(size_t)s0.x * D + lane];
        float xs1 = cur[(size_t)s1.x * D + lane];
        float xs2 = cur[(size_t)s2.x * D + lane];
        float xs3 = cur[(size_t)s3.x * D + lane];
        accG = fmaf(__int_as_float(g0.y), xg0, accG);
        accG = fmaf(__int_as_float(g1.y), xg1, accG);
        accG = fmaf(__int_as_float(g2.y), xg2, accG);
        accG = fmaf(__int_as_float(g3.y), xg3, accG);
        accS = fmaf(__int_as_float(s0.y), xs0, accS);
        accS = fmaf(__int_as_float(s1.y), xs1, accS);
        accS = fmaf(__int_as_float(s2.y), xs2, accS);
        accS = fmaf(__int_as_float(s3.y), xs3, accS);
        pG += 4; pS += 4;
    }
    accG = rowGather(svG, pG, eG, cur, lane, accG);
    accS = rowGather(svS, pS, eS, cur, lane, accS);

    float t1 = accG * c + accG;
    float t2 = accS * c + accS;
    #pragma unroll
    for (int off = 32; off; off >>= 1) {
        t1 += __shfl_xor(t1, off, 64);
        t2 += __shfl_xor(t2, off, 64);
    }
    float a1 = expf(t1 * (1.0f / 64.0f));
    float a2 = expf(t2 * (1.0f / 64.0f));
    float den = a1 + a2;
    float nv = (a1 / den) * accG + (a2 / den) * accS;
    nxt[base] = nv;
}

// ---------------------------------------------------------------------------
// final: mean of 4 layer embeddings at sampled rows, then dot
// ---------------------------------------------------------------------------
__global__ __launch_bounds__(256) void final_dot(const float* __restrict__ c0,
                                                 const float* __restrict__ c1,
                                                 const float* __restrict__ c2,
                                                 const float* __restrict__ c3,
                                                 const int* __restrict__ users,
                                                 const int* __restrict__ items,
                                                 float* __restrict__ out) {
    const int lane = threadIdx.x & 63;
    int b = blockIdx.x * (blockDim.x >> 6) + (threadIdx.x >> 6);
    if (b >= BB) return;
    size_t ub = (size_t)users[b] * D + lane;
    size_t vb = (size_t)(N_USER + items[b]) * D + lane;
    float x = (c0[ub] + c1[ub] + c2[ub] + c3[ub]) * 0.25f;
    float y = (c0[vb] + c1[vb] + c2[vb] + c3[vb]) * 0.25f;
    float p = x * y;
    #pragma unroll
    for (int off = 32; off; off >>= 1) p += __shfl_xor(p, off, 64);
    if (lane == 0) out[b] = p;
}

extern "C" void kernel_launch(void* const* d_in, const int* in_sizes, int n_in,
                              void* d_out, int out_size, void* d_ws, size_t ws_size,
                              hipStream_t stream) {
    const float* ue   = (const float*)d_in[0];
    const float* ie   = (const float*)d_in[1];
    const int*   gsrc = (const int*)d_in[2];
    const int*   gdst = (const int*)d_in[3];
    const float* gval = (const float*)d_in[4];
    const int*   ssrc = (const int*)d_in[5];
    const int*   sdst = (const int*)d_in[6];
    const float* sval = (const float*)d_in[7];
    const int*   users = (const int*)d_in[8];
    const int*   items = (const int*)d_in[9];
    float* out = (float*)d_out;

    // ---- workspace carve-up ----
    char* p = (char*)d_ws;
    auto carve = [&](size_t bytes) { char* r = p; p += (bytes + 255) & ~(size_t)255; return r; };
    const size_t rowElems = (size_t)NTOT * D;                    // 9.6M floats
    float* cur[LAYERS + 1];
    for (int l = 0; l <= LAYERS; ++l) cur[l] = (float*)carve(rowElems * 4);  // 153.6 MB
    int2*  svG   = (int2*)carve((size_t)NE * 8);                 // 19.2 MB
    int2*  svS   = (int2*)carve((size_t)NE * 8);                 // 19.2 MB
    int*   rpG   = (int*)carve((size_t)(NTOT + 1) * 4);
    int*   rpS   = (int*)carve((size_t)(NTOT + 1) * 4);
    int*   bucketCount = (int*)carve((size_t)NBUCK * 4);
    int*   bucketBase  = (int*)carve((size_t)NBUCK * 4);
    // bucketBuf (28.8 MB) aliases cur[3]+ svG headroom? NO — alias onto cur[3]:
    // cur[3] (38.4 MB) is first written in layer 3, strictly after both builds.
    int2*  bucketBuf = (int2*)cur[3];
    (void)ws_size;

    init_emb<<<(NTOT * D / 4 + 255) / 256, 256, 0, stream>>>(ue, ie, cur[0]);

    // ---- radix CSR build for both edge sets ----
    const int* esrc[2] = {gsrc, ssrc};
    const int* edst[2] = {gdst, sdst};
    const float* eval[2] = {gval, sval};
    int2* sv[2] = {svG, svS};
    int*  rp[2] = {rpG, rpS};
    for (int s = 0; s < 2; ++s) {
        hipMemsetAsync(bucketCount, 0, (size_t)NBUCK * 4, stream);
        partition_edges<<<PART_GRID, 256, 0, stream>>>(esrc[s], edst[s], eval[s],
                                                       bucketCount, bucketBuf);
        bucket_scan<<<1, 1024, 0, stream>>>(bucketCount, bucketBase, rp[s]);
        bucket_build<<<NBUCK, 256, 0, stream>>>(bucketBuf, bucketCount, bucketBase,
                                                rp[s], sv[s]);
    }

    // ---- 3 fused propagation layers (double-buffered) ----
    for (int l = 0; l < LAYERS; ++l) {
        layer_fused<<<(NTOT + 3) / 4, 256, 0, stream>>>(svG, rpG, svS, rpS,
                                                        cur[l], cur[l + 1]);
    }

    final_dot<<<BB / 4, 256, 0, stream>>>(cur[0], cur[1], cur[2], cur[3],
                                          users, items, out);
}